// Round 5
// baseline (262.969 us; speedup 1.0000x reference)
//
#include <hip/hip_runtime.h>

static constexpr int HID = 32;
static constexpr int LEN = 32768;
static constexpr int NKL = 128;
static constexpr int HOP = 256;
#define SLOPE 0.2f

typedef short short8 __attribute__((ext_vector_type(8)));
typedef float floatx4 __attribute__((ext_vector_type(4)));
typedef unsigned int u32;

// ---------------- LDS map (main kernel), one __shared__ char arena ----------------
//   [0, 17792)       xs_t: 278 rows x 64 B (32 bf16), XOR-swizzled (row&7)<<4
//                    ys_t: rows 0..273, same layout/swizzle   [conv epi..LVC]
//                    os  : 32 rows x 264 bf16 (528 B row), linear [post-LVC]
//   [17792, 31104)   b2: LVC weights [o(64)][104 bf16] (208 B row), linear
static constexpr int XROW  = 64;
static constexpr int WOFF  = 17792;             // = 278 * 64
static constexpr int WROW  = 208;
static constexpr int WSLAB = 64 * WROW;         // 13312 = 13 x 1024 gload_lds chunks
static constexpr int OSROW = 528;
static constexpr int SMEMB = WOFF + WSLAB;      // 31104 -> 5 blocks/CU

__device__ __forceinline__ int xsw(int row, int bcol) {
    return ((row << 6) + bcol) ^ ((row & 7) << 4);
}

// ---------------- workspace layout (ushort elements) ----------------
static constexpr size_t KT_USH  = (size_t)16 * NKL * 64 * 104;
static constexpr size_t CWT_OFF = KT_USH;

__device__ __forceinline__ float leaky(float x) { return fmaxf(x, SLOPE * x); }

__device__ __forceinline__ unsigned short f2bf(float f) {
    union { float f; unsigned u; } v; v.f = f;
    unsigned r = v.u + 0x7FFFu + ((v.u >> 16) & 1u);   // RNE
    return (unsigned short)(r >> 16);
}
__device__ __forceinline__ float bf2f(unsigned short s) {
    union { unsigned u; float f; } v; v.u = ((unsigned)s) << 16;
    return v.f;
}
__device__ __forceinline__ u32 cvtpk(float lo, float hi) {
    u32 r;
    asm("v_cvt_pk_bf16_f32 %0, %1, %2" : "=v"(r) : "v"(lo), "v"(hi));
    return r;
}
__device__ __forceinline__ float rcp_fast(float x) {   // 1 ulp, inf->0 (exact limit)
    float r; asm("v_rcp_f32 %0, %1" : "=v"(r) : "v"(x)); return r;
}
// sigmoid(a)*tanh(c): tanh via 1 - 2/(1+e^{2c}); saturates correctly at +-inf
__device__ __forceinline__ float gatef(float a, float c) {
    float sg = rcp_fast(1.0f + __expf(-a));
    float t  = fmaf(-2.0f, rcp_fast(1.0f + __expf(2.0f * c)), 1.0f);
    return sg * t;
}

// =====================================================================================
// Pre-pass (unchanged): kern [b][i][o][k][kl] f32 -> kt [b][kl][o][104] bf16
// =====================================================================================
__global__ __launch_bounds__(256) void prep_kern(
    const float* __restrict__ kern,    // [16][32][64][3][128]
    const float* __restrict__ cw,      // [32][32][3]
    unsigned short* __restrict__ kt)   // workspace
{
    const int blk = blockIdx.x;        // 1024 = b*64 + o
    const int b = blk >> 6, o = blk & 63;
    const int tid = threadIdx.x;
    __shared__ unsigned short lt[32 * 384];    // [i][kk*128 + kl] bf16

    const float* src = kern + (size_t)(b * 2048 + o) * 384;
    #pragma unroll
    for (int j = 0; j < 12; ++j) {
        const int f = tid + 256 * j;
        const int i = f / 96, r = f - i * 96;
        float4 v = *(const float4*)(src + (size_t)i * 24576 + (size_t)r * 4);
        uint2 pk2 = make_uint2(cvtpk(v.x, v.y), cvtpk(v.z, v.w));
        *(uint2*)(lt + i * 384 + r * 4) = pk2;
    }

    if (blk == 0) {   // conv weights -> cwt[o2][kk*32+i]
        #pragma unroll
        for (int j = 0; j < 12; ++j) {
            const int d = tid + 256 * j;
            const int o2 = d / 96, rr = d - o2 * 96;
            const int kk = rr >> 5, i = rr & 31;
            kt[CWT_OFF + d] = f2bf(cw[(o2 * 32 + i) * 3 + kk]);
        }
    }
    __syncthreads();

    const int kl = tid >> 1, half = tid & 1;
    u32 wbuf[24];
    #pragma unroll
    for (int m = 0; m < 24; ++m) {
        const int c0 = half * 48 + 2 * m;
        const int kk = c0 >> 5, i0 = c0 & 31;
        u32 lo = lt[i0 * 384 + kk * 128 + kl];
        u32 hi = lt[(i0 + 1) * 384 + kk * 128 + kl];
        wbuf[m] = lo | (hi << 16);
    }
    unsigned short* dst = kt + ((size_t)(b * NKL + kl) * 64 + o) * 104 + half * 48;
    #pragma unroll
    for (int m = 0; m < 6; ++m)
        ((uint4*)dst)[m] = make_uint4(wbuf[4*m], wbuf[4*m+1], wbuf[4*m+2], wbuf[4*m+3]);
}

// =====================================================================================
// Main kernel
// =====================================================================================
__global__ __launch_bounds__(256, 5) void univnet_mfma(
    const float* __restrict__ h,      // [16][32][32768]
    const float* __restrict__ bias,   // [16][64][128]
    const float* __restrict__ cb,     // [32]
    float* __restrict__ out,
    const unsigned short* __restrict__ kt)
{
    __shared__ __align__(16) char smem[SMEMB];

    const int blk = blockIdx.x;           // 2048
    const int b   = blk & 15;             // XCD-pinned: blk%8 == b%8
    const int kl  = blk >> 4;
    const int t0  = kl * HOP;
    const int p0  = t0 - 4;
    const int tid = threadIdx.x;
    const int w   = tid >> 6;
    const int lane = tid & 63;
    const int l15 = lane & 15;
    const int l4  = lane >> 4;

    const float* hb = h + (size_t)b * (HID * LEN);

    // ---- async-stage LVC weight slab into LDS (linear dest, drained at s0) ----
    {
        const char* slab = (const char*)kt + (size_t)(b * NKL + kl) * WSLAB;
        #pragma unroll
        for (int j = 0; j < 4; ++j) {
            const int c = w + 4 * j;
            if (c < 13)
                __builtin_amdgcn_global_load_lds(
                    (const u32 __attribute__((address_space(1)))*)(slab + c * 1024 + lane * 16),
                    (u32 __attribute__((address_space(3)))*)(smem + WOFF + c * 1024),
                    16, 0, 0);
        }
    }

    // ---- prefetch conv-weight frags + biases ----
    const unsigned short* cwt = kt + CWT_OFF;
    short8 b1f[2][3];
    #pragma unroll
    for (int tn = 0; tn < 2; ++tn)
        #pragma unroll
        for (int qk = 0; qk < 3; ++qk)
            b1f[tn][qk] = *(const short8*)(cwt + (tn * 16 + l15) * 96 + qk * 32 + l4 * 8);
    float4 cbq[2];
    cbq[0] = *(const float4*)(cb + l4 * 4);
    cbq[1] = *(const float4*)(cb + 16 + l4 * 4);
    float bv[2][2];
    #pragma unroll
    for (int pp = 0; pp < 2; ++pp) {
        bv[pp][0] = bias[((size_t)b * 64 + pp * 16 + l15) * NKL + kl];
        bv[pp][1] = bias[((size_t)b * 64 + pp * 16 + l15 + 32) * NKL + kl];
    }

    // ============ Phase A: stage leaky(h) transposed + keep raw h in regs ============
    // Task tau = tid+4 (cq = tid/4+1 in 1..64, oct = tid&3): positions
    // p = t0 + 4*(tid>>2) + e are ALWAYS in [t0, t0+255] -> no edge guard.
    // Residual kept in EIGHT NAMED float4 scalars (rule #20: an ext_vector ARRAY
    // goes to scratch even with unrolled indices -- named scalars are the fix).
    float4 hf0, hf1, hf2, hf3, hf4, hf5, hf6, hf7;
    {
        const int oct = tid & 3, cq = (tid >> 2) + 1;
        const float* hp0 = hb + p0 + 4 * cq;
        u32 pk[4][4];
#define STAGE_JP(JP, HFA, HFB)                                                  \
        {                                                                       \
            const int i0 = oct * 8 + 2 * (JP);                                  \
            float4 f0 = *(const float4*)(hp0 + (size_t)i0 * LEN);               \
            float4 f1 = *(const float4*)(hp0 + (size_t)(i0 + 1) * LEN);         \
            HFA = f0; HFB = f1;                                                 \
            pk[0][JP] = cvtpk(leaky(f0.x), leaky(f1.x));                        \
            pk[1][JP] = cvtpk(leaky(f0.y), leaky(f1.y));                        \
            pk[2][JP] = cvtpk(leaky(f0.z), leaky(f1.z));                        \
            pk[3][JP] = cvtpk(leaky(f0.w), leaky(f1.w));                        \
        }
        STAGE_JP(0, hf0, hf1)
        STAGE_JP(1, hf2, hf3)
        STAGE_JP(2, hf4, hf5)
        STAGE_JP(3, hf6, hf7)
#undef STAGE_JP
        #pragma unroll
        for (int e = 0; e < 4; ++e)
            *(uint4*)(smem + xsw(4 * cq + e, oct * 16)) =
                make_uint4(pk[e][0], pk[e][1], pk[e][2], pk[e][3]);
    }
    // Leftover halo tasks {0..3, 260..263} (cq = 0 or 65): guarded scalar loads.
    if (tid < 8) {
        const int tau = (tid < 4) ? tid : (256 + tid);
        const int oct = tau & 3, cq = tau >> 2;
        u32 pk[4][4];
        #pragma unroll
        for (int jp = 0; jp < 4; ++jp) {
            const int i0 = oct * 8 + 2 * jp;
            #pragma unroll
            for (int e = 0; e < 4; ++e) {
                const int p = p0 + 4 * cq + e;
                float a = 0.0f, c2 = 0.0f;
                if ((unsigned)p < (unsigned)LEN) {
                    a  = hb[(size_t)i0 * LEN + p];
                    c2 = hb[(size_t)(i0 + 1) * LEN + p];
                }
                pk[e][jp] = cvtpk(leaky(a), leaky(c2));
            }
        }
        #pragma unroll
        for (int e = 0; e < 4; ++e)
            *(uint4*)(smem + xsw(4 * cq + e, oct * 16)) =
                make_uint4(pk[e][0], pk[e][1], pk[e][2], pk[e][3]);
    }
    // zero pad rows 264..277 (bytes [16896, 17792))
    if (tid < 224) ((u32*)(smem + 16896))[tid] = 0u;

    __syncthreads();   // s0: xs_t + b2 slab ready

    // ================= Conv GEMM (operand-swapped => C^T layout) ====================
    floatx4 cacc[9];
    #pragma unroll
    for (int n = 0; n < 9; ++n) {
        const int tt = w + 4 * n;
        if (tt < 34) {
            const int tm = tt >> 1, tn = tt & 1;
            short8 af[3];
            #pragma unroll
            for (int qk = 0; qk < 3; ++qk)
                af[qk] = *(const short8*)(smem + xsw(tm * 16 + l15 + 3 * qk, l4 * 16));
            floatx4 acc = {cbq[tn].x, cbq[tn].y, cbq[tn].z, cbq[tn].w};
            #pragma unroll
            for (int qk = 0; qk < 3; ++qk)
                acc = __builtin_amdgcn_mfma_f32_16x16x32_bf16(b1f[tn][qk], af[qk], acc, 0, 0, 0);
            cacc[n] = acc;
        }
    }
    __syncthreads();   // s1: conv reads done; xs_t dead

    // ---- conv epilogue: cvt_pk pair + one 8-B store per tile, swizzled ----
    #pragma unroll
    for (int n = 0; n < 9; ++n) {
        const int tt = w + 4 * n;
        if (tt < 34) {
            const int tm = tt >> 1, tn = tt & 1;
            const int c_out = tm * 16 + l15;
            const int p = t0 - 1 + c_out;
            u32 q0 = 0u, q1 = 0u;
            if ((unsigned)p < (unsigned)LEN) {
                q0 = cvtpk(leaky(cacc[n][0]), leaky(cacc[n][1]));
                q1 = cvtpk(leaky(cacc[n][2]), leaky(cacc[n][3]));
            }
            *(uint2*)(smem + xsw(c_out, tn * 32 + l4 * 8)) = make_uint2(q0, q1);
        }
    }
    __syncthreads();   // s2: ys_t ready

    // ================= LVC GEMM: [256 x 96] * [96 x 64], gate in-reg ================
    unsigned garr[2][4][2];
    #pragma unroll
    for (int pp = 0; pp < 2; ++pp) {
        const int oA = pp * 16 + l15, oB = oA + 32;
        short8 b2A[3], b2B[3];
        #pragma unroll
        for (int qk = 0; qk < 3; ++qk) {
            b2A[qk] = *(const short8*)(smem + WOFF + oA * WROW + (qk * 32 + l4 * 8) * 2);
            b2B[qk] = *(const short8*)(smem + WOFF + oB * WROW + (qk * 32 + l4 * 8) * 2);
        }
        const float bA = bv[pp][0], bB = bv[pp][1];
        #pragma unroll
        for (int t = 0; t < 4; ++t) {
            const int tm = 4 * t + w;
            short8 af[3];
            #pragma unroll
            for (int qk = 0; qk < 3; ++qk)
                af[qk] = *(const short8*)(smem + xsw(tm * 16 + l15 + qk, l4 * 16));
            floatx4 aA = {bA, bA, bA, bA}, aB = {bB, bB, bB, bB};
            #pragma unroll
            for (int qk = 0; qk < 3; ++qk) {
                aA = __builtin_amdgcn_mfma_f32_16x16x32_bf16(af[qk], b2A[qk], aA, 0, 0, 0);
                aB = __builtin_amdgcn_mfma_f32_16x16x32_bf16(af[qk], b2B[qk], aB, 0, 0, 0);
            }
            #pragma unroll
            for (int hp = 0; hp < 2; ++hp)
                garr[pp][t][hp] =
                    cvtpk(gatef(aA[2 * hp], aB[2 * hp]), gatef(aA[2 * hp + 1], aB[2 * hp + 1]));
        }
    }
    __syncthreads();   // s3: LVC reads done; ys_t dead

    // ---- scatter gates to os[o][s] (bf16, linear) ----
    #pragma unroll
    for (int pp = 0; pp < 2; ++pp) {
        const int o = pp * 16 + l15;
        #pragma unroll
        for (int t = 0; t < 4; ++t) {
            const int sbase = (4 * t + w) * 16 + l4 * 4;
            #pragma unroll
            for (int hp = 0; hp < 2; ++hp)
                *(u32*)(smem + o * OSROW + (sbase + 2 * hp) * 2) = garr[pp][t][hp];
        }
    }
    __syncthreads();   // s4

    // ======== Epilogue: out = h(reg) + gate(os), per-thread staging footprint =======
    // ch = (tid&3)*8 + 2jp+half, positions t0+scol..t0+scol+3, scol = 4*(tid>>2).
    // Per store instruction each oct-group covers 16 lanes x 16 B contiguous,
    // 64 B-aligned -> full lines only. Named hf scalars -> pure register reads.
    {
        const int woct = tid & 3;
        const int scol = 4 * (tid >> 2);           // 0..252
        float* ob = out + (size_t)b * (HID * LEN) + t0 + scol;
#define EPI(JP, HALF, HV)                                                       \
        {                                                                       \
            const int ch = woct * 8 + 2 * (JP) + (HALF);                        \
            uint2 g = *(const uint2*)(smem + ch * OSROW + scol * 2);            \
            float4 ov;                                                          \
            ov.x = HV.x + bf2f((unsigned short)(g.x & 0xffff));                 \
            ov.y = HV.y + bf2f((unsigned short)(g.x >> 16));                    \
            ov.z = HV.z + bf2f((unsigned short)(g.y & 0xffff));                 \
            ov.w = HV.w + bf2f((unsigned short)(g.y >> 16));                    \
            *(float4*)(ob + (size_t)ch * LEN) = ov;                             \
        }
        EPI(0, 0, hf0) EPI(0, 1, hf1)
        EPI(1, 0, hf2) EPI(1, 1, hf3)
        EPI(2, 0, hf4) EPI(2, 1, hf5)
        EPI(3, 0, hf6) EPI(3, 1, hf7)
#undef EPI
    }
}

extern "C" void kernel_launch(void* const* d_in, const int* in_sizes, int n_in,
                              void* d_out, int out_size, void* d_ws, size_t ws_size,
                              hipStream_t stream) {
    const float* h    = (const float*)d_in[0];
    const float* kern = (const float*)d_in[1];
    const float* bias = (const float*)d_in[2];
    const float* cw   = (const float*)d_in[3];
    const float* cb   = (const float*)d_in[4];
    float* outp = (float*)d_out;
    unsigned short* kt = (unsigned short*)d_ws;   // ~26.1 MB workspace

    prep_kern<<<1024, 256, 0, stream>>>(kern, cw, kt);
    univnet_mfma<<<2048, 256, 0, stream>>>(h, bias, cb, outp, kt);
}

// Round 6
// 217.648 us; speedup vs baseline: 1.2082x; 1.2082x over previous
//
#include <hip/hip_runtime.h>

static constexpr int HID = 32;
static constexpr int LEN = 32768;
static constexpr int NKL = 128;
static constexpr int HOP = 256;
#define SLOPE 0.2f

typedef short short8 __attribute__((ext_vector_type(8)));
typedef float floatx4 __attribute__((ext_vector_type(4)));
typedef unsigned int u32;

// ---------------- LDS map (main kernel), one __shared__ char arena ----------------
//   [0, 17792)       xs_t: 278 rows x 64 B (32 bf16), XOR-swizzled (row&7)<<4
//                    ys_t: rows 0..273, same layout/swizzle   [conv epi..LVC]
//                    os  : 32 rows x 264 bf16 (528 B row), linear [post-LVC]
//   [17792, 31104)   b2: LVC weights [o(64)][104 bf16] (208 B row), linear
static constexpr int XROW  = 64;
static constexpr int WOFF  = 17792;             // = 278 * 64
static constexpr int WROW  = 208;
static constexpr int WSLAB = 64 * WROW;         // 13312 = 13 x 1024 gload_lds chunks
static constexpr int OSROW = 528;
static constexpr int SMEMB = WOFF + WSLAB;      // 31104 -> 5 blocks/CU

__device__ __forceinline__ int xsw(int row, int bcol) {
    return ((row << 6) + bcol) ^ ((row & 7) << 4);
}

// ---------------- workspace layout (ushort elements) ----------------
static constexpr size_t KT_USH  = (size_t)16 * NKL * 64 * 104;
static constexpr size_t CWT_OFF = KT_USH;

__device__ __forceinline__ float leaky(float x) { return fmaxf(x, SLOPE * x); }

__device__ __forceinline__ unsigned short f2bf(float f) {
    union { float f; unsigned u; } v; v.f = f;
    unsigned r = v.u + 0x7FFFu + ((v.u >> 16) & 1u);   // RNE
    return (unsigned short)(r >> 16);
}
__device__ __forceinline__ float bf2f(unsigned short s) {
    union { unsigned u; float f; } v; v.u = ((unsigned)s) << 16;
    return v.f;
}
__device__ __forceinline__ u32 cvtpk(float lo, float hi) {
    u32 r;
    asm("v_cvt_pk_bf16_f32 %0, %1, %2" : "=v"(r) : "v"(lo), "v"(hi));
    return r;
}
__device__ __forceinline__ float rcp_fast(float x) {   // 1 ulp, inf->0 (exact limit)
    float r; asm("v_rcp_f32 %0, %1" : "=v"(r) : "v"(x)); return r;
}
// sigmoid(a)*tanh(c): tanh via 1 - 2/(1+e^{2c}); saturates correctly at +-inf
__device__ __forceinline__ float gatef(float a, float c) {
    float sg = rcp_fast(1.0f + __expf(-a));
    float t  = fmaf(-2.0f, rcp_fast(1.0f + __expf(2.0f * c)), 1.0f);
    return sg * t;
}

// =====================================================================================
// Pre-pass v2: kern [b][i][o][k][kl] f32 -> kt [b][kl][o][104] bf16.
// R1-R5's write phase scattered 64 lines per store instruction (lanes 13312 B apart,
// 1.6M line-requests for 26 MB). v2 linearizes: store id s in [0,1664), 16 B each;
// 208 = 13*16 so stores never straddle a (kl,o)-row; consecutive lanes hit
// consecutive addresses in 208 B runs -> ~4x fewer line transactions, full lines.
// LDS tile rows padded 384->386 (4 B-aligned u32 writes; transpose-gather lane-stride
// 8*386*2 B -> bank step 8 -> <=4-way conflicts).
// =====================================================================================
__global__ __launch_bounds__(256) void prep_kern(
    const float* __restrict__ kern,    // [16][32][64][3][128]
    const float* __restrict__ cw,      // [32][32][3]
    unsigned short* __restrict__ kt)   // workspace
{
    const int blk = blockIdx.x;        // 1024 = b*64 + o
    const int b = blk >> 6, o = blk & 63;
    const int tid = threadIdx.x;
    __shared__ unsigned short lt[32 * 386];    // [i][kk*128 + kl] bf16, row 386

    // coalesced load of the (b,o) slice: per i, 384 contiguous floats
    const float* src = kern + (size_t)(b * 2048 + o) * 384;
    #pragma unroll
    for (int j = 0; j < 12; ++j) {
        const int f = tid + 256 * j;           // float4 id < 3072
        const int i = f / 96, r = f - i * 96;
        float4 v = *(const float4*)(src + (size_t)i * 24576 + (size_t)r * 4);
        // two u32 writes (row stride 386 ushorts => only 4 B-aligned)
        *(u32*)(lt + i * 386 + r * 4)     = cvtpk(v.x, v.y);
        *(u32*)(lt + i * 386 + r * 4 + 2) = cvtpk(v.z, v.w);
    }

    if (blk == 0) {   // conv weights -> cwt[o2][kk*32+i]
        #pragma unroll
        for (int j = 0; j < 12; ++j) {
            const int d = tid + 256 * j;       // < 3072
            const int o2 = d / 96, rr = d - o2 * 96;
            const int kk = rr >> 5, i = rr & 31;
            kt[CWT_OFF + d] = f2bf(cw[(o2 * 32 + i) * 3 + kk]);
        }
    }
    __syncthreads();

    // linear write-out: s -> (kl = s/13, q = s%13); 16 B per store.
    // dst ushort idx = ((b*128+kl)*64 + o)*104 + 8q ; cols 96..103 (q==12) zero-pad.
    unsigned short* slab = kt + (size_t)b * (NKL * 64 * 104) + (size_t)o * 104;
    #pragma unroll
    for (int j = 0; j < 7; ++j) {
        const int s = tid + 256 * j;           // < 1792, guard at 1664
        if (s < 1664) {
            const int kl = s / 13, q = s - kl * 13;
            uint4 d = make_uint4(0u, 0u, 0u, 0u);
            if (q < 12) {
                const int kk = q >> 2;         // cols 8q..8q+7 stay in one kk (8|32)
                const int ib = 8 * (q & 3);    // i = ib..ib+7
                const unsigned short* p = lt + kk * 128 + kl;
                d.x = (u32)p[(ib + 0) * 386] | ((u32)p[(ib + 1) * 386] << 16);
                d.y = (u32)p[(ib + 2) * 386] | ((u32)p[(ib + 3) * 386] << 16);
                d.z = (u32)p[(ib + 4) * 386] | ((u32)p[(ib + 5) * 386] << 16);
                d.w = (u32)p[(ib + 6) * 386] | ((u32)p[(ib + 7) * 386] << 16);
            }
            *(uint4*)(slab + (size_t)kl * 6656 + 8 * q) = d;
        }
    }
}

// =====================================================================================
// Main kernel — byte-identical to R2 (verified 83.4 us)
// =====================================================================================
__global__ __launch_bounds__(256, 5) void univnet_mfma(
    const float* __restrict__ h,      // [16][32][32768]
    const float* __restrict__ bias,   // [16][64][128]
    const float* __restrict__ cb,     // [32]
    float* __restrict__ out,
    const unsigned short* __restrict__ kt)
{
    __shared__ __align__(16) char smem[SMEMB];

    const int blk = blockIdx.x;           // 2048
    const int b   = blk & 15;             // XCD-pinned: blk%8 == b%8
    const int kl  = blk >> 4;
    const int t0  = kl * HOP;
    const int p0  = t0 - 4;
    const int tid = threadIdx.x;
    const int w   = tid >> 6;
    const int lane = tid & 63;
    const int l15 = lane & 15;
    const int l4  = lane >> 4;

    const float* hb = h + (size_t)b * (HID * LEN);
    const bool edge = (kl == 0) || (kl == NKL - 1);

    // ---- async-stage LVC weight slab into LDS (linear dest, drained at s0) ----
    {
        const char* slab = (const char*)kt + (size_t)(b * NKL + kl) * WSLAB;
        #pragma unroll
        for (int j = 0; j < 4; ++j) {
            const int c = w + 4 * j;
            if (c < 13)
                __builtin_amdgcn_global_load_lds(
                    (const u32 __attribute__((address_space(1)))*)(slab + c * 1024 + lane * 16),
                    (u32 __attribute__((address_space(3)))*)(smem + WOFF + c * 1024),
                    16, 0, 0);
        }
    }

    // ---- prefetch conv-weight frags + biases ----
    const unsigned short* cwt = kt + CWT_OFF;
    short8 b1f[2][3];
    #pragma unroll
    for (int tn = 0; tn < 2; ++tn)
        #pragma unroll
        for (int qk = 0; qk < 3; ++qk)
            b1f[tn][qk] = *(const short8*)(cwt + (tn * 16 + l15) * 96 + qk * 32 + l4 * 8);
    float4 cbq[2];
    cbq[0] = *(const float4*)(cb + l4 * 4);
    cbq[1] = *(const float4*)(cb + 16 + l4 * 4);
    float bv[2][2];
    #pragma unroll
    for (int pp = 0; pp < 2; ++pp) {
        bv[pp][0] = bias[((size_t)b * 64 + pp * 16 + l15) * NKL + kl];
        bv[pp][1] = bias[((size_t)b * 64 + pp * 16 + l15 + 32) * NKL + kl];
    }

    // ================= Phase A: stage leaky(h) transposed, swizzled ================
    {
        auto stage = [&](int tau) {
            const int oct = tau & 3, cq = tau >> 2;
            u32 pk[4][4];
            if (!edge) {
                #pragma unroll
                for (int jp = 0; jp < 4; ++jp) {
                    const int i0 = oct * 8 + 2 * jp;
                    float4 f0 = *(const float4*)(hb + (size_t)i0 * LEN + p0 + 4 * cq);
                    float4 f1 = *(const float4*)(hb + (size_t)(i0 + 1) * LEN + p0 + 4 * cq);
                    pk[0][jp] = cvtpk(leaky(f0.x), leaky(f1.x));
                    pk[1][jp] = cvtpk(leaky(f0.y), leaky(f1.y));
                    pk[2][jp] = cvtpk(leaky(f0.z), leaky(f1.z));
                    pk[3][jp] = cvtpk(leaky(f0.w), leaky(f1.w));
                }
            } else {
                #pragma unroll
                for (int jp = 0; jp < 4; ++jp) {
                    const int i0 = oct * 8 + 2 * jp;
                    #pragma unroll
                    for (int e = 0; e < 4; ++e) {
                        const int p = p0 + 4 * cq + e;
                        float a = 0.0f, c2 = 0.0f;
                        if ((unsigned)p < (unsigned)LEN) {
                            a  = hb[(size_t)i0 * LEN + p];
                            c2 = hb[(size_t)(i0 + 1) * LEN + p];
                        }
                        pk[e][jp] = cvtpk(leaky(a), leaky(c2));
                    }
                }
            }
            #pragma unroll
            for (int e = 0; e < 4; ++e)
                *(uint4*)(smem + xsw(4 * cq + e, oct * 16)) =
                    make_uint4(pk[e][0], pk[e][1], pk[e][2], pk[e][3]);
        };
        stage(tid);
        if (tid < 8) stage(256 + tid);
        // zero pad rows 264..277 (bytes [16896, 17792))
        if (tid < 224) ((u32*)(smem + 16896))[tid] = 0u;
    }

    __syncthreads();   // s0: xs_t + b2 slab ready

    // ================= Conv GEMM (operand-swapped => C^T layout) ====================
    floatx4 cacc[9];
    #pragma unroll
    for (int n = 0; n < 9; ++n) {
        const int tt = w + 4 * n;
        if (tt < 34) {
            const int tm = tt >> 1, tn = tt & 1;
            short8 af[3];
            #pragma unroll
            for (int qk = 0; qk < 3; ++qk)
                af[qk] = *(const short8*)(smem + xsw(tm * 16 + l15 + 3 * qk, l4 * 16));
            floatx4 acc = {cbq[tn].x, cbq[tn].y, cbq[tn].z, cbq[tn].w};
            #pragma unroll
            for (int qk = 0; qk < 3; ++qk)
                acc = __builtin_amdgcn_mfma_f32_16x16x32_bf16(b1f[tn][qk], af[qk], acc, 0, 0, 0);
            cacc[n] = acc;
        }
    }
    __syncthreads();   // s1: conv reads done; xs_t dead

    // ---- conv epilogue: cvt_pk pair + one 8-B store per tile, swizzled ----
    #pragma unroll
    for (int n = 0; n < 9; ++n) {
        const int tt = w + 4 * n;
        if (tt < 34) {
            const int tm = tt >> 1, tn = tt & 1;
            const int c_out = tm * 16 + l15;
            const int p = t0 - 1 + c_out;
            u32 q0 = 0u, q1 = 0u;
            if ((unsigned)p < (unsigned)LEN) {
                q0 = cvtpk(leaky(cacc[n][0]), leaky(cacc[n][1]));
                q1 = cvtpk(leaky(cacc[n][2]), leaky(cacc[n][3]));
            }
            *(uint2*)(smem + xsw(c_out, tn * 32 + l4 * 8)) = make_uint2(q0, q1);
        }
    }
    __syncthreads();   // s2: ys_t ready

    // ================= LVC GEMM: [256 x 96] * [96 x 64], gate in-reg ================
    unsigned garr[2][4][2];
    #pragma unroll
    for (int pp = 0; pp < 2; ++pp) {
        const int oA = pp * 16 + l15, oB = oA + 32;
        short8 b2A[3], b2B[3];
        #pragma unroll
        for (int qk = 0; qk < 3; ++qk) {
            b2A[qk] = *(const short8*)(smem + WOFF + oA * WROW + (qk * 32 + l4 * 8) * 2);
            b2B[qk] = *(const short8*)(smem + WOFF + oB * WROW + (qk * 32 + l4 * 8) * 2);
        }
        const float bA = bv[pp][0], bB = bv[pp][1];
        #pragma unroll
        for (int t = 0; t < 4; ++t) {
            const int tm = 4 * t + w;
            short8 af[3];
            #pragma unroll
            for (int qk = 0; qk < 3; ++qk)
                af[qk] = *(const short8*)(smem + xsw(tm * 16 + l15 + qk, l4 * 16));
            floatx4 aA = {bA, bA, bA, bA}, aB = {bB, bB, bB, bB};
            #pragma unroll
            for (int qk = 0; qk < 3; ++qk) {
                aA = __builtin_amdgcn_mfma_f32_16x16x32_bf16(af[qk], b2A[qk], aA, 0, 0, 0);
                aB = __builtin_amdgcn_mfma_f32_16x16x32_bf16(af[qk], b2B[qk], aB, 0, 0, 0);
            }
            #pragma unroll
            for (int hp = 0; hp < 2; ++hp)
                garr[pp][t][hp] =
                    cvtpk(gatef(aA[2 * hp], aB[2 * hp]), gatef(aA[2 * hp + 1], aB[2 * hp + 1]));
        }
    }
    __syncthreads();   // s3: LVC reads done; ys_t dead

    // ---- scatter gates to os[o][s] (bf16, linear) ----
    #pragma unroll
    for (int pp = 0; pp < 2; ++pp) {
        const int o = pp * 16 + l15;
        #pragma unroll
        for (int t = 0; t < 4; ++t) {
            const int sbase = (4 * t + w) * 16 + l4 * 4;
            #pragma unroll
            for (int hp = 0; hp < 2; ++hp)
                *(u32*)(smem + o * OSROW + (sbase + 2 * hp) * 2) = garr[pp][t][hp];
        }
    }
    __syncthreads();   // s4

    // ================= Epilogue: out = h + gate, coalesced ================
    {
        const int eo = tid >> 3, e8 = tid & 7;
        const float* hrow = hb + (size_t)eo * LEN + t0;
        float* orow = out + ((size_t)b * HID + eo) * LEN + t0;
        #pragma unroll
        for (int rep = 0; rep < 8; ++rep) {
            const int s = e8 * 4 + 32 * rep;
            uint2 g = *(const uint2*)(smem + eo * OSROW + s * 2);
            float4 hv = *(const float4*)(hrow + s);
            float4 ov;
            ov.x = hv.x + bf2f((unsigned short)(g.x & 0xffff));
            ov.y = hv.y + bf2f((unsigned short)(g.x >> 16));
            ov.z = hv.z + bf2f((unsigned short)(g.y & 0xffff));
            ov.w = hv.w + bf2f((unsigned short)(g.y >> 16));
            *(float4*)(orow + s) = ov;
        }
    }
}

extern "C" void kernel_launch(void* const* d_in, const int* in_sizes, int n_in,
                              void* d_out, int out_size, void* d_ws, size_t ws_size,
                              hipStream_t stream) {
    const float* h    = (const float*)d_in[0];
    const float* kern = (const float*)d_in[1];
    const float* bias = (const float*)d_in[2];
    const float* cw   = (const float*)d_in[3];
    const float* cb   = (const float*)d_in[4];
    float* outp = (float*)d_out;
    unsigned short* kt = (unsigned short*)d_ws;   // ~26.1 MB workspace

    prep_kern<<<1024, 256, 0, stream>>>(kern, cw, kt);
    univnet_mfma<<<2048, 256, 0, stream>>>(h, bias, cb, outp, kt);
}

// Round 7
// 216.218 us; speedup vs baseline: 1.2162x; 1.0066x over previous
//
#include <hip/hip_runtime.h>

static constexpr int HID = 32;
static constexpr int LEN = 32768;
static constexpr int NKL = 128;
static constexpr int HOP = 256;
#define SLOPE 0.2f

typedef short short8 __attribute__((ext_vector_type(8)));
typedef float floatx4 __attribute__((ext_vector_type(4)));
typedef unsigned int u32;

// ---------------- LDS map (main kernel), one __shared__ char arena ----------------
//   [0, 17792)       xs_t: 278 rows x 64 B (32 bf16), XOR-swizzled (row&7)<<4
//                    ys_t: rows 0..273, same layout/swizzle   [conv epi..LVC]
//   [17792, 31104)   b2: LVC weights [o(64)][104 bf16] (208 B row), linear
//   (no os buffer: gates go straight from registers to global)
static constexpr int XROW  = 64;
static constexpr int WOFF  = 17792;             // = 278 * 64
static constexpr int WROW  = 208;
static constexpr int WSLAB = 64 * WROW;         // 13312 = 13 x 1024 gload_lds chunks
static constexpr int SMEMB = WOFF + WSLAB;      // 31104 -> 5 blocks/CU

__device__ __forceinline__ int xsw(int row, int bcol) {
    return ((row << 6) + bcol) ^ ((row & 7) << 4);
}

// ---------------- workspace layout (ushort elements) ----------------
static constexpr size_t KT_USH  = (size_t)16 * NKL * 64 * 104;
static constexpr size_t CWT_OFF = KT_USH;

__device__ __forceinline__ float leaky(float x) { return fmaxf(x, SLOPE * x); }

__device__ __forceinline__ unsigned short f2bf(float f) {
    union { float f; unsigned u; } v; v.f = f;
    unsigned r = v.u + 0x7FFFu + ((v.u >> 16) & 1u);   // RNE
    return (unsigned short)(r >> 16);
}
__device__ __forceinline__ u32 cvtpk(float lo, float hi) {
    u32 r;
    asm("v_cvt_pk_bf16_f32 %0, %1, %2" : "=v"(r) : "v"(lo), "v"(hi));
    return r;
}
__device__ __forceinline__ float rcp_fast(float x) {   // 1 ulp, inf->0 (exact limit)
    float r; asm("v_rcp_f32 %0, %1" : "=v"(r) : "v"(x)); return r;
}
// sigmoid(a)*tanh(c): tanh via 1 - 2/(1+e^{2c}); saturates correctly at +-inf
__device__ __forceinline__ float gatef(float a, float c) {
    float sg = rcp_fast(1.0f + __expf(-a));
    float t  = fmaf(-2.0f, rcp_fast(1.0f + __expf(2.0f * c)), 1.0f);
    return sg * t;
}

// =====================================================================================
// Pre-pass v2 (unchanged from R6): kern -> kt [b][kl][o][104] bf16, linearized stores
// =====================================================================================
__global__ __launch_bounds__(256) void prep_kern(
    const float* __restrict__ kern,    // [16][32][64][3][128]
    const float* __restrict__ cw,      // [32][32][3]
    unsigned short* __restrict__ kt)   // workspace
{
    const int blk = blockIdx.x;        // 1024 = b*64 + o
    const int b = blk >> 6, o = blk & 63;
    const int tid = threadIdx.x;
    __shared__ unsigned short lt[32 * 386];    // [i][kk*128 + kl] bf16, row 386

    const float* src = kern + (size_t)(b * 2048 + o) * 384;
    #pragma unroll
    for (int j = 0; j < 12; ++j) {
        const int f = tid + 256 * j;           // float4 id < 3072
        const int i = f / 96, r = f - i * 96;
        float4 v = *(const float4*)(src + (size_t)i * 24576 + (size_t)r * 4);
        *(u32*)(lt + i * 386 + r * 4)     = cvtpk(v.x, v.y);
        *(u32*)(lt + i * 386 + r * 4 + 2) = cvtpk(v.z, v.w);
    }

    if (blk == 0) {   // conv weights -> cwt[o2][kk*32+i]
        #pragma unroll
        for (int j = 0; j < 12; ++j) {
            const int d = tid + 256 * j;       // < 3072
            const int o2 = d / 96, rr = d - o2 * 96;
            const int kk = rr >> 5, i = rr & 31;
            kt[CWT_OFF + d] = f2bf(cw[(o2 * 32 + i) * 3 + kk]);
        }
    }
    __syncthreads();

    unsigned short* slab = kt + (size_t)b * (NKL * 64 * 104) + (size_t)o * 104;
    #pragma unroll
    for (int j = 0; j < 7; ++j) {
        const int s = tid + 256 * j;           // < 1792, guard at 1664
        if (s < 1664) {
            const int kl = s / 13, q = s - kl * 13;
            uint4 d = make_uint4(0u, 0u, 0u, 0u);
            if (q < 12) {
                const int kk = q >> 2;
                const int ib = 8 * (q & 3);
                const unsigned short* p = lt + kk * 128 + kl;
                d.x = (u32)p[(ib + 0) * 386] | ((u32)p[(ib + 1) * 386] << 16);
                d.y = (u32)p[(ib + 2) * 386] | ((u32)p[(ib + 3) * 386] << 16);
                d.z = (u32)p[(ib + 4) * 386] | ((u32)p[(ib + 5) * 386] << 16);
                d.w = (u32)p[(ib + 6) * 386] | ((u32)p[(ib + 7) * 386] << 16);
            }
            *(uint4*)(slab + (size_t)kl * 6656 + 8 * q) = d;
        }
    }
}

// =====================================================================================
// Main kernel: 3 barriers. Back half fused: LVC MFMA -> gate(f32) -> +h -> store,
// all in registers (os scatter + s3/s4 + epilogue deleted).
// =====================================================================================
__global__ __launch_bounds__(256, 5) void univnet_mfma(
    const float* __restrict__ h,      // [16][32][32768]
    const float* __restrict__ bias,   // [16][64][128]
    const float* __restrict__ cb,     // [32]
    float* __restrict__ out,
    const unsigned short* __restrict__ kt)
{
    __shared__ __align__(16) char smem[SMEMB];

    const int blk = blockIdx.x;           // 2048
    const int b   = blk & 15;             // XCD-pinned: blk%8 == b%8
    const int kl  = blk >> 4;
    const int t0  = kl * HOP;
    const int p0  = t0 - 4;
    const int tid = threadIdx.x;
    const int w   = tid >> 6;
    const int lane = tid & 63;
    const int l15 = lane & 15;
    const int l4  = lane >> 4;

    const float* hb = h + (size_t)b * (HID * LEN);
    const bool edge = (kl == 0) || (kl == NKL - 1);

    // ---- async-stage LVC weight slab into LDS (linear dest, drained at s0) ----
    {
        const char* slab = (const char*)kt + (size_t)(b * NKL + kl) * WSLAB;
        #pragma unroll
        for (int j = 0; j < 4; ++j) {
            const int c = w + 4 * j;
            if (c < 13)
                __builtin_amdgcn_global_load_lds(
                    (const u32 __attribute__((address_space(1)))*)(slab + c * 1024 + lane * 16),
                    (u32 __attribute__((address_space(3)))*)(smem + WOFF + c * 1024),
                    16, 0, 0);
        }
    }

    // ---- prefetch conv-weight frags + biases ----
    const unsigned short* cwt = kt + CWT_OFF;
    short8 b1f[2][3];
    #pragma unroll
    for (int tn = 0; tn < 2; ++tn)
        #pragma unroll
        for (int qk = 0; qk < 3; ++qk)
            b1f[tn][qk] = *(const short8*)(cwt + (tn * 16 + l15) * 96 + qk * 32 + l4 * 8);
    float4 cbq[2];
    cbq[0] = *(const float4*)(cb + l4 * 4);
    cbq[1] = *(const float4*)(cb + 16 + l4 * 4);
    float bv[2][2];
    #pragma unroll
    for (int pp = 0; pp < 2; ++pp) {
        bv[pp][0] = bias[((size_t)b * 64 + pp * 16 + l15) * NKL + kl];
        bv[pp][1] = bias[((size_t)b * 64 + pp * 16 + l15 + 32) * NKL + kl];
    }

    // ================= Phase A: stage leaky(h) transposed, swizzled ================
    {
        auto stage = [&](int tau) {
            const int oct = tau & 3, cq = tau >> 2;
            u32 pk[4][4];
            if (!edge) {
                #pragma unroll
                for (int jp = 0; jp < 4; ++jp) {
                    const int i0 = oct * 8 + 2 * jp;
                    float4 f0 = *(const float4*)(hb + (size_t)i0 * LEN + p0 + 4 * cq);
                    float4 f1 = *(const float4*)(hb + (size_t)(i0 + 1) * LEN + p0 + 4 * cq);
                    pk[0][jp] = cvtpk(leaky(f0.x), leaky(f1.x));
                    pk[1][jp] = cvtpk(leaky(f0.y), leaky(f1.y));
                    pk[2][jp] = cvtpk(leaky(f0.z), leaky(f1.z));
                    pk[3][jp] = cvtpk(leaky(f0.w), leaky(f1.w));
                }
            } else {
                #pragma unroll
                for (int jp = 0; jp < 4; ++jp) {
                    const int i0 = oct * 8 + 2 * jp;
                    #pragma unroll
                    for (int e = 0; e < 4; ++e) {
                        const int p = p0 + 4 * cq + e;
                        float a = 0.0f, c2 = 0.0f;
                        if ((unsigned)p < (unsigned)LEN) {
                            a  = hb[(size_t)i0 * LEN + p];
                            c2 = hb[(size_t)(i0 + 1) * LEN + p];
                        }
                        pk[e][jp] = cvtpk(leaky(a), leaky(c2));
                    }
                }
            }
            #pragma unroll
            for (int e = 0; e < 4; ++e)
                *(uint4*)(smem + xsw(4 * cq + e, oct * 16)) =
                    make_uint4(pk[e][0], pk[e][1], pk[e][2], pk[e][3]);
        };
        stage(tid);
        if (tid < 8) stage(256 + tid);
        // zero pad rows 264..277 (bytes [16896, 17792))
        if (tid < 224) ((u32*)(smem + 16896))[tid] = 0u;
    }

    __syncthreads();   // s0: xs_t + b2 slab ready

    // ================= Conv GEMM (operand-swapped => C^T layout) ====================
    floatx4 cacc[9];
    #pragma unroll
    for (int n = 0; n < 9; ++n) {
        const int tt = w + 4 * n;
        if (tt < 34) {
            const int tm = tt >> 1, tn = tt & 1;
            short8 af[3];
            #pragma unroll
            for (int qk = 0; qk < 3; ++qk)
                af[qk] = *(const short8*)(smem + xsw(tm * 16 + l15 + 3 * qk, l4 * 16));
            floatx4 acc = {cbq[tn].x, cbq[tn].y, cbq[tn].z, cbq[tn].w};
            #pragma unroll
            for (int qk = 0; qk < 3; ++qk)
                acc = __builtin_amdgcn_mfma_f32_16x16x32_bf16(b1f[tn][qk], af[qk], acc, 0, 0, 0);
            cacc[n] = acc;
        }
    }
    __syncthreads();   // s1: conv reads done; xs_t dead

    // ---- conv epilogue: cvt_pk pair + one 8-B store per tile, swizzled ----
    #pragma unroll
    for (int n = 0; n < 9; ++n) {
        const int tt = w + 4 * n;
        if (tt < 34) {
            const int tm = tt >> 1, tn = tt & 1;
            const int c_out = tm * 16 + l15;
            const int p = t0 - 1 + c_out;
            u32 q0 = 0u, q1 = 0u;
            if ((unsigned)p < (unsigned)LEN) {
                q0 = cvtpk(leaky(cacc[n][0]), leaky(cacc[n][1]));
                q1 = cvtpk(leaky(cacc[n][2]), leaky(cacc[n][3]));
            }
            *(uint2*)(smem + xsw(c_out, tn * 32 + l4 * 8)) = make_uint2(q0, q1);
        }
    }
    __syncthreads();   // s2: ys_t ready (last barrier)

    // ======= LVC GEMM fused with output: gate(f32) + h + store, all in regs ========
    // Lane owns ch = pp*16+l15 (sigmoid half; +32 is tanh half), positions
    // t*64 + w*16 + l4*4 + {0..3} for t=0..3 -- tiles [t0, t0+256) exactly.
    // h prefetch issued at top of each pp-iteration, hidden under 12 MFMAs.
    #pragma unroll
    for (int pp = 0; pp < 2; ++pp) {
        const int oA = pp * 16 + l15, oB = oA + 32;
        // h prefetch (4 x float4, named -> registers; 16 full lines per instr)
        const float* hrow = hb + (size_t)oA * LEN + t0 + w * 16 + l4 * 4;
        const float4 h0 = *(const float4*)(hrow);
        const float4 h1 = *(const float4*)(hrow + 64);
        const float4 h2 = *(const float4*)(hrow + 128);
        const float4 h3 = *(const float4*)(hrow + 192);
        short8 b2A[3], b2B[3];
        #pragma unroll
        for (int qk = 0; qk < 3; ++qk) {
            b2A[qk] = *(const short8*)(smem + WOFF + oA * WROW + (qk * 32 + l4 * 8) * 2);
            b2B[qk] = *(const short8*)(smem + WOFF + oB * WROW + (qk * 32 + l4 * 8) * 2);
        }
        const float bA = bv[pp][0], bB = bv[pp][1];
        float* orow = out + ((size_t)b * HID + oA) * LEN + t0 + w * 16 + l4 * 4;
#define LVC_T(T, HV)                                                            \
        {                                                                       \
            const int tm = 4 * (T) + w;                                         \
            short8 af0 = *(const short8*)(smem + xsw(tm * 16 + l15,     l4 * 16)); \
            short8 af1 = *(const short8*)(smem + xsw(tm * 16 + l15 + 1, l4 * 16)); \
            short8 af2 = *(const short8*)(smem + xsw(tm * 16 + l15 + 2, l4 * 16)); \
            floatx4 aA = {bA, bA, bA, bA}, aB = {bB, bB, bB, bB};               \
            aA = __builtin_amdgcn_mfma_f32_16x16x32_bf16(af0, b2A[0], aA, 0, 0, 0); \
            aB = __builtin_amdgcn_mfma_f32_16x16x32_bf16(af0, b2B[0], aB, 0, 0, 0); \
            aA = __builtin_amdgcn_mfma_f32_16x16x32_bf16(af1, b2A[1], aA, 0, 0, 0); \
            aB = __builtin_amdgcn_mfma_f32_16x16x32_bf16(af1, b2B[1], aB, 0, 0, 0); \
            aA = __builtin_amdgcn_mfma_f32_16x16x32_bf16(af2, b2A[2], aA, 0, 0, 0); \
            aB = __builtin_amdgcn_mfma_f32_16x16x32_bf16(af2, b2B[2], aB, 0, 0, 0); \
            float4 ov;                                                          \
            ov.x = HV.x + gatef(aA[0], aB[0]);                                  \
            ov.y = HV.y + gatef(aA[1], aB[1]);                                  \
            ov.z = HV.z + gatef(aA[2], aB[2]);                                  \
            ov.w = HV.w + gatef(aA[3], aB[3]);                                  \
            *(float4*)(orow + (T) * 64) = ov;                                   \
        }
        LVC_T(0, h0)
        LVC_T(1, h1)
        LVC_T(2, h2)
        LVC_T(3, h3)
#undef LVC_T
    }
    // kernel ends here: stores are fire-and-forget, no tail barrier
}

extern "C" void kernel_launch(void* const* d_in, const int* in_sizes, int n_in,
                              void* d_out, int out_size, void* d_ws, size_t ws_size,
                              hipStream_t stream) {
    const float* h    = (const float*)d_in[0];
    const float* kern = (const float*)d_in[1];
    const float* bias = (const float*)d_in[2];
    const float* cw   = (const float*)d_in[3];
    const float* cb   = (const float*)d_in[4];
    float* outp = (float*)d_out;
    unsigned short* kt = (unsigned short*)d_ws;   // ~26.1 MB workspace

    prep_kern<<<1024, 256, 0, stream>>>(kern, cw, kt);
    univnet_mfma<<<2048, 256, 0, stream>>>(h, bias, cb, outp, kt);
}